// Round 4
// baseline (1701.234 us; speedup 1.0000x reference)
//
#include <hip/hip_runtime.h>
#include <hip/hip_bf16.h>

#define FIN 512
#define HD 32
#define BNODES 512     // nodes per dst-bucket (bucket = dst >> 9)
#define CH 4096        // edges per bin chunk

// ---------------- degree ----------------
__global__ __launch_bounds__(256) void k_deg_init(int* deg, int N) {
  int i = blockIdx.x * 256 + threadIdx.x;
  if (i < N) deg[i] = 1;  // self-loop
}

__global__ __launch_bounds__(256) void k_deg_count(const int* __restrict__ dst, int* deg, int E) {
  int i = blockIdx.x * 256 + threadIdx.x;
  int stride = gridDim.x * 256;
  for (; i < E; i += stride) atomicAdd(&deg[dst[i]], 1);
}

__global__ __launch_bounds__(256) void k_dis(const int* __restrict__ deg, float* dis, int N) {
  int i = blockIdx.x * 256 + threadIdx.x;
  if (i < N) dis[i] = rsqrtf((float)deg[i]);
}

// ---------------- bucket counts: bcnt[b] = sum over bucket of (deg-1) ----------------
__global__ __launch_bounds__(512) void k_bucketcnt(const int* __restrict__ deg, int* bcnt, int N) {
  __shared__ int s[512];
  int t = threadIdx.x;
  int n = blockIdx.x * BNODES + t;
  s[t] = (n < N) ? deg[n] - 1 : 0;
  __syncthreads();
  for (int o = 256; o; o >>= 1) { if (t < o) s[t] += s[t + o]; __syncthreads(); }
  if (t == 0) bcnt[blockIdx.x] = s[0];
}

// exclusive scan over B (<=256) buckets; init fill cursors
__global__ __launch_bounds__(256) void k_bscan(const int* __restrict__ bcnt, int* bbase, int* bfill, int B) {
  __shared__ int s[256];
  int t = threadIdx.x;
  int v = (t < B) ? bcnt[t] : 0;
  s[t] = v;
  __syncthreads();
  for (int o = 1; o < 256; o <<= 1) {
    int a = (t >= o) ? s[t - o] : 0;
    __syncthreads();
    s[t] += a;
    __syncthreads();
  }
  if (t < B) { bbase[t] = s[t] - v; bfill[t] = s[t] - v; }
}

// ---------------- coarse binning: bin[] gets (src,dst) grouped by dst-bucket ----------------
// Chunk edges through LDS; per chunk: histogram -> one global cursor bump per
// bucket -> scatter. Runs within a chunk are contiguous (~170B) and written in
// a tight window by one block -> lines fill in L2 before writeback.
__global__ __launch_bounds__(256) void k_bin(const int* __restrict__ src, const int* __restrict__ dst,
                                             int* __restrict__ bfill, int2* __restrict__ bin, int E) {
  __shared__ int2 raw[CH];     // 32 KB
  __shared__ int cnt[256];
  __shared__ int gbase[256];
  int t = threadIdx.x;
  for (int cb = blockIdx.x * CH; cb < E; cb += gridDim.x * CH) {
    int n = E - cb; if (n > CH) n = CH;
    cnt[t] = 0;
    __syncthreads();
    for (int j = t; j < n; j += 256) {
      int s = src[cb + j], d = dst[cb + j];
      raw[j] = make_int2(s, d);
      atomicAdd(&cnt[d >> 9], 1);
    }
    __syncthreads();
    int c = cnt[t];
    int gb = (c > 0) ? atomicAdd(&bfill[t], c) : 0;
    gbase[t] = gb;
    cnt[t] = 0;  // reuse as in-chunk cursor
    __syncthreads();
    for (int j = t; j < n; j += 256) {
      int2 e = raw[j];
      int b = e.y >> 9;
      int r = atomicAdd(&cnt[b], 1);
      bin[gbase[b] + r] = e;
    }
    __syncthreads();
  }
}

// ---------------- mm1: h1 = x @ W1, register-tiled fp32 (unchanged from R3) ----------------
#define KC 32
#define XSP 33
__global__ __launch_bounds__(256, 4) void k_mm1(const float* __restrict__ x, const float* __restrict__ W1,
                                                float* __restrict__ h1, int N) {
  __shared__ float xs[128 * XSP];
  __shared__ float wc[KC * HD];
  const int t = threadIdx.x;

  const int wv = t >> 6;
  const int lane = t & 63;
  const int rg = lane >> 3, cg = lane & 7;
  const int rbase = blockIdx.x * 128;
  const int arow = wv * 32 + rg * 4;

  const int ss = t & 7;
  const int sq = t >> 3;

  float acc[4][4];
#pragma unroll
  for (int i = 0; i < 4; ++i)
#pragma unroll
    for (int j = 0; j < 4; ++j) acc[i][j] = 0.f;

  for (int kc = 0; kc < FIN; kc += KC) {
    __syncthreads();
    ((float4*)wc)[t] = ((const float4*)(W1 + kc * HD))[t];
#pragma unroll
    for (int p = 0; p < 4; ++p) {
      int r = p * 32 + sq;
      int grow = rbase + r;
      float4 v = make_float4(0.f, 0.f, 0.f, 0.f);
      if (grow < N) v = *(const float4*)&x[(size_t)grow * FIN + kc + ss * 4];
      float* xr = &xs[r * XSP + ss * 4];
      xr[0] = v.x; xr[1] = v.y; xr[2] = v.z; xr[3] = v.w;
    }
    __syncthreads();

#pragma unroll 8
    for (int k = 0; k < KC; ++k) {
      float4 b = *(const float4*)&wc[k * HD + cg * 4];
      float a0 = xs[(arow + 0) * XSP + k];
      float a1 = xs[(arow + 1) * XSP + k];
      float a2 = xs[(arow + 2) * XSP + k];
      float a3 = xs[(arow + 3) * XSP + k];
      acc[0][0] += a0 * b.x; acc[0][1] += a0 * b.y; acc[0][2] += a0 * b.z; acc[0][3] += a0 * b.w;
      acc[1][0] += a1 * b.x; acc[1][1] += a1 * b.y; acc[1][2] += a1 * b.z; acc[1][3] += a1 * b.w;
      acc[2][0] += a2 * b.x; acc[2][1] += a2 * b.y; acc[2][2] += a2 * b.z; acc[2][3] += a2 * b.w;
      acc[3][0] += a3 * b.x; acc[3][1] += a3 * b.y; acc[3][2] += a3 * b.z; acc[3][3] += a3 * b.w;
    }
  }

#pragma unroll
  for (int i = 0; i < 4; ++i) {
    int row = rbase + arow + i;
    if (row < N)
      *(float4*)&h1[(size_t)row * HD + cg * 4] = make_float4(acc[i][0], acc[i][1], acc[i][2], acc[i][3]);
  }
}

// ---------------- layer1: bucketized pull (LDS agg) + bias + relu + mm2 -> h2 ----------------
__global__ __launch_bounds__(512) void k_pull1_mm2(const float* __restrict__ h1, const int2* __restrict__ bin,
                                                   const int* __restrict__ bbase, const int* __restrict__ bcnt,
                                                   const float* __restrict__ dis, const float* __restrict__ b1,
                                                   const float* __restrict__ W2, float* __restrict__ h2, int N) {
  __shared__ float agg[BNODES * HD];   // 64 KB
  __shared__ float disl[BNODES];
  __shared__ float w[HD * HD];
  __shared__ float bb[HD];
  const int t = threadIdx.x;
  const int bkt = blockIdx.x;
  const int n0 = bkt * BNODES;
  int nn = N - n0; if (nn > BNODES) nn = BNODES;

  if (t < HD) bb[t] = b1[t];
  for (int i = t; i < HD * HD; i += 512) w[i] = W2[i];
  for (int i = t; i < nn; i += 512) disl[i] = dis[n0 + i];
  __syncthreads();
  // self-loop init: agg[r][c] = h1[n0+r][c] * dis^2
  for (int i = t; i < nn * HD; i += 512) {
    int r = i >> 5;
    float dd = disl[r];
    agg[i] = h1[(size_t)(n0 + r) * HD + (i & 31)] * dd * dd;
  }
  __syncthreads();

  const int c = t & 31, hw = t >> 5;  // 16 half-waves
  const int eb = bbase[bkt], ec = bcnt[bkt];
  int j = hw;
  for (; j + 16 < ec; j += 32) {  // unroll 2 for ILP
    int2 e0 = bin[eb + j], e1 = bin[eb + j + 16];
    float n0r = dis[e0.x] * disl[e0.y - n0];
    float n1r = dis[e1.x] * disl[e1.y - n0];
    float g0 = h1[(size_t)e0.x * HD + c];
    float g1 = h1[(size_t)e1.x * HD + c];
    unsafeAtomicAdd(&agg[(e0.y - n0) * HD + c], g0 * n0r);
    unsafeAtomicAdd(&agg[(e1.y - n0) * HD + c], g1 * n1r);
  }
  if (j < ec) {
    int2 e0 = bin[eb + j];
    float n0r = dis[e0.x] * disl[e0.y - n0];
    float g0 = h1[(size_t)e0.x * HD + c];
    unsafeAtomicAdd(&agg[(e0.y - n0) * HD + c], g0 * n0r);
  }
  __syncthreads();

  for (int r = hw; r < nn; r += 16) {
    float tv = fmaxf(agg[r * HD + c] + bb[c], 0.f);
    float a2 = 0.f;
#pragma unroll
    for (int k = 0; k < HD; ++k) a2 += __shfl(tv, k, 32) * w[k * HD + c];
    h2[(size_t)(n0 + r) * HD + c] = a2;
  }
}

// ---------------- layer2: bucketized pull + bias + log_softmax -> out ----------------
__global__ __launch_bounds__(512) void k_pull2_lsm(const float* __restrict__ h2, const int2* __restrict__ bin,
                                                   const int* __restrict__ bbase, const int* __restrict__ bcnt,
                                                   const float* __restrict__ dis, const float* __restrict__ b2,
                                                   float* __restrict__ out, int N) {
  __shared__ float agg[BNODES * HD];
  __shared__ float disl[BNODES];
  __shared__ float bb[HD];
  const int t = threadIdx.x;
  const int bkt = blockIdx.x;
  const int n0 = bkt * BNODES;
  int nn = N - n0; if (nn > BNODES) nn = BNODES;

  if (t < HD) bb[t] = b2[t];
  for (int i = t; i < nn; i += 512) disl[i] = dis[n0 + i];
  __syncthreads();
  for (int i = t; i < nn * HD; i += 512) {
    int r = i >> 5;
    float dd = disl[r];
    agg[i] = h2[(size_t)(n0 + r) * HD + (i & 31)] * dd * dd;
  }
  __syncthreads();

  const int c = t & 31, hw = t >> 5;
  const int eb = bbase[bkt], ec = bcnt[bkt];
  int j = hw;
  for (; j + 16 < ec; j += 32) {
    int2 e0 = bin[eb + j], e1 = bin[eb + j + 16];
    float n0r = dis[e0.x] * disl[e0.y - n0];
    float n1r = dis[e1.x] * disl[e1.y - n0];
    float g0 = h2[(size_t)e0.x * HD + c];
    float g1 = h2[(size_t)e1.x * HD + c];
    unsafeAtomicAdd(&agg[(e0.y - n0) * HD + c], g0 * n0r);
    unsafeAtomicAdd(&agg[(e1.y - n0) * HD + c], g1 * n1r);
  }
  if (j < ec) {
    int2 e0 = bin[eb + j];
    float n0r = dis[e0.x] * disl[e0.y - n0];
    float g0 = h2[(size_t)e0.x * HD + c];
    unsafeAtomicAdd(&agg[(e0.y - n0) * HD + c], g0 * n0r);
  }
  __syncthreads();

  for (int r = hw; r < nn; r += 16) {
    float v = agg[r * HD + c] + bb[c];
    float m = v;
    for (int off = 16; off; off >>= 1) m = fmaxf(m, __shfl_xor(m, off, 32));
    float ex = __expf(v - m);
    float s = ex;
    for (int off = 16; off; off >>= 1) s += __shfl_xor(s, off, 32);
    out[(size_t)(n0 + r) * HD + c] = v - m - __logf(s);
  }
}

extern "C" void kernel_launch(void* const* d_in, const int* in_sizes, int n_in,
                              void* d_out, int out_size, void* d_ws, size_t ws_size,
                              hipStream_t stream) {
  const float* x  = (const float*)d_in[0];
  const int*   ei = (const int*)d_in[1];
  const float* W1 = (const float*)d_in[2];
  const float* b1 = (const float*)d_in[3];
  const float* W2 = (const float*)d_in[4];
  const float* b2 = (const float*)d_in[5];
  float* out = (float*)d_out;

  const int H   = in_sizes[3];            // 32
  const int Fin = in_sizes[2] / H;        // 512
  const int N   = in_sizes[0] / Fin;      // 100000
  const int E   = in_sizes[1] / 2;        // 3200000
  const int* src = ei;
  const int* dst = ei + E;
  const int B   = (N + BNODES - 1) / BNODES;  // 196 buckets

  char* wsp = (char*)d_ws;
  size_t off = 0;
  auto nxt = [&](size_t bytes) { char* p = wsp + off; off = (off + bytes + 255) & ~(size_t)255; return p; };
  int*   deg   = (int*)  nxt((size_t)N * 4);
  float* dis   = (float*)nxt((size_t)N * 4);
  int*   bcnt  = (int*)  nxt(256 * 4);
  int*   bbase = (int*)  nxt(256 * 4);
  int*   bfill = (int*)  nxt(256 * 4);
  int2*  bin   = (int2*) nxt((size_t)E * 8);
  float* h1    = (float*)nxt((size_t)N * HD * 4);
  float* h2    = (float*)nxt((size_t)N * HD * 4);
  (void)ws_size; (void)n_in; (void)out_size;

  int gN = (N + 255) / 256;

  k_deg_init<<<gN, 256, 0, stream>>>(deg, N);
  k_deg_count<<<2048, 256, 0, stream>>>(dst, deg, E);
  k_dis<<<gN, 256, 0, stream>>>(deg, dis, N);
  k_bucketcnt<<<B, 512, 0, stream>>>(deg, bcnt, N);
  k_bscan<<<1, 256, 0, stream>>>(bcnt, bbase, bfill, B);
  k_bin<<<256, 256, 0, stream>>>(src, dst, bfill, bin, E);
  k_mm1<<<(N + 127) / 128, 256, 0, stream>>>(x, W1, h1, N);
  k_pull1_mm2<<<B, 512, 0, stream>>>(h1, bin, bbase, bcnt, dis, b1, W2, h2, N);
  k_pull2_lsm<<<B, 512, 0, stream>>>(h2, bin, bbase, bcnt, dis, b2, out, N);
}

// Round 5
// 475.888 us; speedup vs baseline: 3.5749x; 3.5749x over previous
//
#include <hip/hip_runtime.h>
#include <hip/hip_bf16.h>

#define FIN 512
#define HD 32
#define BNODES 512   // nodes per dst-bucket (bucket = dst >> 9)
#define CH 8192      // edges per bin chunk

// ---------------- degree ----------------
__global__ __launch_bounds__(256) void k_deg_init(int* deg, int N) {
  int i = blockIdx.x * 256 + threadIdx.x;
  if (i < N) deg[i] = 1;  // self-loop
}

__global__ __launch_bounds__(256) void k_deg_count(const int* __restrict__ dst, int* deg, int E) {
  int i = blockIdx.x * 256 + threadIdx.x;
  int stride = gridDim.x * 256;
  for (; i < E; i += stride) atomicAdd(&deg[dst[i]], 1);
}

__global__ __launch_bounds__(256) void k_dis(const int* __restrict__ deg, float* dis, int N) {
  int i = blockIdx.x * 256 + threadIdx.x;
  if (i < N) dis[i] = rsqrtf((float)deg[i]);
}

// ---------------- bucket counts: bcnt[b] = sum over bucket of (deg-1) ----------------
__global__ __launch_bounds__(512) void k_bucketcnt(const int* __restrict__ deg, int* bcnt, int N) {
  __shared__ int s[512];
  int t = threadIdx.x;
  int n = blockIdx.x * BNODES + t;
  s[t] = (n < N) ? deg[n] - 1 : 0;
  __syncthreads();
  for (int o = 256; o; o >>= 1) { if (t < o) s[t] += s[t + o]; __syncthreads(); }
  if (t == 0) bcnt[blockIdx.x] = s[0];
}

// exclusive scan over B (<=256) buckets; init fill cursors
__global__ __launch_bounds__(256) void k_bscan(const int* __restrict__ bcnt, int* bbase, int* bfill, int B) {
  __shared__ int s[256];
  int t = threadIdx.x;
  int v = (t < B) ? bcnt[t] : 0;
  s[t] = v;
  __syncthreads();
  for (int o = 1; o < 256; o <<= 1) {
    int a = (t >= o) ? s[t - o] : 0;
    __syncthreads();
    s[t] += a;
    __syncthreads();
  }
  if (t < B) { bbase[t] = s[t] - v; bfill[t] = s[t] - v; }
}

// ---------------- phase 1: coarse bin (src,dst) grouped by dst-bucket ----------------
// Runs within a chunk are ~42 entries = 336B contiguous -> mostly full 64B lines.
__global__ __launch_bounds__(512) void k_bin(const int* __restrict__ src, const int* __restrict__ dst,
                                             int* __restrict__ bfill, int2* __restrict__ bin, int E) {
  __shared__ int2 raw[CH];     // 64 KB
  __shared__ int cnt[256];
  __shared__ int gbase[256];
  int t = threadIdx.x;
  for (int cb = blockIdx.x * CH; cb < E; cb += gridDim.x * CH) {
    int n = E - cb; if (n > CH) n = CH;
    if (t < 256) cnt[t] = 0;
    __syncthreads();
    for (int j = t; j < n; j += 512) {
      int s = src[cb + j], d = dst[cb + j];
      raw[j] = make_int2(s, d);
      atomicAdd(&cnt[d >> 9], 1);
    }
    __syncthreads();
    if (t < 256) {
      int c = cnt[t];
      gbase[t] = (c > 0) ? atomicAdd(&bfill[t], c) : 0;
      cnt[t] = 0;  // reuse as in-chunk cursor
    }
    __syncthreads();
    for (int j = t; j < n; j += 512) {
      int2 e = raw[j];
      int b = e.y >> 9;
      int r = atomicAdd(&cnt[b], 1);
      bin[gbase[b] + r] = e;
    }
    __syncthreads();
  }
}

// ---------------- phase 2: per-bucket exact CSR + offsets + norm ----------------
// Scatter target = bucket's contiguous ~128KB csr region: L2-hot, lines fill
// before writeback. Also emits offsets[] (replaces global scan kernels).
__global__ __launch_bounds__(512) void k_csr(const int2* __restrict__ bin, const int* __restrict__ bbase,
                                             const int* __restrict__ bcnt, const float* __restrict__ dis,
                                             int* __restrict__ offsets, int2* __restrict__ csr, int N) {
  __shared__ int cnt[BNODES];
  __shared__ int sc[BNODES];
  __shared__ float disl[BNODES];
  const int t = threadIdx.x;
  const int bkt = blockIdx.x;
  const int n0 = bkt * BNODES;
  int nn = N - n0; if (nn > BNODES) nn = BNODES;
  const int eb = bbase[bkt], ec = bcnt[bkt];

  cnt[t] = 0;
  if (t < nn) disl[t] = dis[n0 + t];
  __syncthreads();
  for (int j = t; j < ec; j += 512)
    atomicAdd(&cnt[bin[eb + j].y - n0], 1);
  __syncthreads();
  int v = cnt[t];
  sc[t] = v;
  __syncthreads();
  for (int o = 1; o < 512; o <<= 1) {
    int a = (t >= o) ? sc[t - o] : 0;
    __syncthreads();
    sc[t] += a;
    __syncthreads();
  }
  int myoff = sc[t] - v;  // exclusive within bucket
  if (t < nn) offsets[n0 + t] = eb + myoff;
  cnt[t] = myoff;         // reuse as scatter cursor
  __syncthreads();
  for (int j = t; j < ec; j += 512) {
    int2 e = bin[eb + j];
    int ld = e.y - n0;
    int pos = atomicAdd(&cnt[ld], 1);
    float nr = dis[e.x] * disl[ld];
    csr[eb + pos] = make_int2(e.x, __float_as_int(nr));
  }
}

// ---------------- mm1: h1 = x @ W1, register-tiled fp32 (R3, unchanged) ----------------
#define KC 32
#define XSP 33
__global__ __launch_bounds__(256, 4) void k_mm1(const float* __restrict__ x, const float* __restrict__ W1,
                                                float* __restrict__ h1, int N) {
  __shared__ float xs[128 * XSP];
  __shared__ float wc[KC * HD];
  const int t = threadIdx.x;

  const int wv = t >> 6;
  const int lane = t & 63;
  const int rg = lane >> 3, cg = lane & 7;
  const int rbase = blockIdx.x * 128;
  const int arow = wv * 32 + rg * 4;

  const int ss = t & 7;
  const int sq = t >> 3;

  float acc[4][4];
#pragma unroll
  for (int i = 0; i < 4; ++i)
#pragma unroll
    for (int j = 0; j < 4; ++j) acc[i][j] = 0.f;

  for (int kc = 0; kc < FIN; kc += KC) {
    __syncthreads();
    ((float4*)wc)[t] = ((const float4*)(W1 + kc * HD))[t];
#pragma unroll
    for (int p = 0; p < 4; ++p) {
      int r = p * 32 + sq;
      int grow = rbase + r;
      float4 v = make_float4(0.f, 0.f, 0.f, 0.f);
      if (grow < N) v = *(const float4*)&x[(size_t)grow * FIN + kc + ss * 4];
      float* xr = &xs[r * XSP + ss * 4];
      xr[0] = v.x; xr[1] = v.y; xr[2] = v.z; xr[3] = v.w;
    }
    __syncthreads();

#pragma unroll 8
    for (int k = 0; k < KC; ++k) {
      float4 b = *(const float4*)&wc[k * HD + cg * 4];
      float a0 = xs[(arow + 0) * XSP + k];
      float a1 = xs[(arow + 1) * XSP + k];
      float a2 = xs[(arow + 2) * XSP + k];
      float a3 = xs[(arow + 3) * XSP + k];
      acc[0][0] += a0 * b.x; acc[0][1] += a0 * b.y; acc[0][2] += a0 * b.z; acc[0][3] += a0 * b.w;
      acc[1][0] += a1 * b.x; acc[1][1] += a1 * b.y; acc[1][2] += a1 * b.z; acc[1][3] += a1 * b.w;
      acc[2][0] += a2 * b.x; acc[2][1] += a2 * b.y; acc[2][2] += a2 * b.z; acc[2][3] += a2 * b.w;
      acc[3][0] += a3 * b.x; acc[3][1] += a3 * b.y; acc[3][2] += a3 * b.z; acc[3][3] += a3 * b.w;
    }
  }

#pragma unroll
  for (int i = 0; i < 4; ++i) {
    int row = rbase + arow + i;
    if (row < N)
      *(float4*)&h1[(size_t)row * HD + cg * 4] = make_float4(acc[i][0], acc[i][1], acc[i][2], acc[i][3]);
  }
}

// ---------------- layer1 pull + bias + relu + mm2 -> h2 (R3, unchanged) ----------------
__global__ __launch_bounds__(256) void k_pull1_mm2(const float* __restrict__ h1, const int2* __restrict__ csr,
                                                   const int* __restrict__ offsets, const int* __restrict__ deg,
                                                   const float* __restrict__ dis, const float* __restrict__ b1,
                                                   const float* __restrict__ W2, float* __restrict__ h2, int N) {
  __shared__ float w[HD * HD];
  __shared__ float bb[HD];
  int t = threadIdx.x;
  if (t < HD) bb[t] = b1[t];
  for (int i = t; i < HD * HD; i += 256) w[i] = W2[i];
  __syncthreads();

  int lane = t & 63, c = lane & 31;
  int halfId = (blockIdx.x * 4 + (t >> 6)) * 2 + (lane >> 5);
  int stride = gridDim.x * 8;
  for (int i = halfId; i < N; i += stride) {
    float d = dis[i];
    float acc = h1[(size_t)i * HD + c] * d * d;  // self-loop
    int jb = offsets[i], cnt = deg[i] - 1;
    int j = 0;
    for (; j + 4 <= cnt; j += 4) {
      int2 e0 = csr[jb + j], e1 = csr[jb + j + 1], e2 = csr[jb + j + 2], e3 = csr[jb + j + 3];
      float g0 = h1[(size_t)e0.x * HD + c];
      float g1 = h1[(size_t)e1.x * HD + c];
      float g2 = h1[(size_t)e2.x * HD + c];
      float g3 = h1[(size_t)e3.x * HD + c];
      acc += g0 * __int_as_float(e0.y) + g1 * __int_as_float(e1.y)
           + g2 * __int_as_float(e2.y) + g3 * __int_as_float(e3.y);
    }
    for (; j < cnt; ++j) {
      int2 e0 = csr[jb + j];
      acc += h1[(size_t)e0.x * HD + c] * __int_as_float(e0.y);
    }
    float tv = fmaxf(acc + bb[c], 0.f);
    float a2 = 0.f;
#pragma unroll
    for (int k = 0; k < HD; ++k) a2 += __shfl(tv, k, 32) * w[k * HD + c];
    h2[(size_t)i * HD + c] = a2;
  }
}

// ---------------- layer2 pull + bias + log_softmax -> out (R3, unchanged) ----------------
__global__ __launch_bounds__(256) void k_pull2_lsm(const float* __restrict__ h2, const int2* __restrict__ csr,
                                                   const int* __restrict__ offsets, const int* __restrict__ deg,
                                                   const float* __restrict__ dis, const float* __restrict__ b2,
                                                   float* __restrict__ out, int N) {
  __shared__ float bb[HD];
  int t = threadIdx.x;
  if (t < HD) bb[t] = b2[t];
  __syncthreads();

  int lane = t & 63, c = lane & 31;
  int halfId = (blockIdx.x * 4 + (t >> 6)) * 2 + (lane >> 5);
  int stride = gridDim.x * 8;
  for (int i = halfId; i < N; i += stride) {
    float d = dis[i];
    float acc = h2[(size_t)i * HD + c] * d * d;  // self-loop
    int jb = offsets[i], cnt = deg[i] - 1;
    int j = 0;
    for (; j + 4 <= cnt; j += 4) {
      int2 e0 = csr[jb + j], e1 = csr[jb + j + 1], e2 = csr[jb + j + 2], e3 = csr[jb + j + 3];
      float g0 = h2[(size_t)e0.x * HD + c];
      float g1 = h2[(size_t)e1.x * HD + c];
      float g2 = h2[(size_t)e2.x * HD + c];
      float g3 = h2[(size_t)e3.x * HD + c];
      acc += g0 * __int_as_float(e0.y) + g1 * __int_as_float(e1.y)
           + g2 * __int_as_float(e2.y) + g3 * __int_as_float(e3.y);
    }
    for (; j < cnt; ++j) {
      int2 e0 = csr[jb + j];
      acc += h2[(size_t)e0.x * HD + c] * __int_as_float(e0.y);
    }
    float v = acc + bb[c];
    float m = v;
    for (int off = 16; off; off >>= 1) m = fmaxf(m, __shfl_xor(m, off, 32));
    float ex = __expf(v - m);
    float s = ex;
    for (int off = 16; off; off >>= 1) s += __shfl_xor(s, off, 32);
    out[(size_t)i * HD + c] = v - m - __logf(s);
  }
}

extern "C" void kernel_launch(void* const* d_in, const int* in_sizes, int n_in,
                              void* d_out, int out_size, void* d_ws, size_t ws_size,
                              hipStream_t stream) {
  const float* x  = (const float*)d_in[0];
  const int*   ei = (const int*)d_in[1];
  const float* W1 = (const float*)d_in[2];
  const float* b1 = (const float*)d_in[3];
  const float* W2 = (const float*)d_in[4];
  const float* b2 = (const float*)d_in[5];
  float* out = (float*)d_out;

  const int H   = in_sizes[3];            // 32
  const int Fin = in_sizes[2] / H;        // 512
  const int N   = in_sizes[0] / Fin;      // 100000
  const int E   = in_sizes[1] / 2;        // 3200000
  const int* src = ei;
  const int* dst = ei + E;
  const int B   = (N + BNODES - 1) / BNODES;  // 196 buckets

  char* wsp = (char*)d_ws;
  size_t off = 0;
  auto nxt = [&](size_t bytes) { char* p = wsp + off; off = (off + bytes + 255) & ~(size_t)255; return p; };
  int*   deg     = (int*)  nxt((size_t)N * 4);
  float* dis     = (float*)nxt((size_t)N * 4);
  int*   bcnt    = (int*)  nxt(256 * 4);
  int*   bbase   = (int*)  nxt(256 * 4);
  int*   bfill   = (int*)  nxt(256 * 4);
  int*   offsets = (int*)  nxt((size_t)N * 4);
  int2*  bin     = (int2*) nxt((size_t)E * 8);
  int2*  csr     = (int2*) nxt((size_t)E * 8);
  float* h1      = (float*)nxt((size_t)N * HD * 4);
  float* h2      = (float*)nxt((size_t)N * HD * 4);
  (void)ws_size; (void)n_in; (void)out_size;

  int gN = (N + 255) / 256;

  k_deg_init<<<gN, 256, 0, stream>>>(deg, N);
  k_deg_count<<<2048, 256, 0, stream>>>(dst, deg, E);
  k_dis<<<gN, 256, 0, stream>>>(deg, dis, N);
  k_bucketcnt<<<B, 512, 0, stream>>>(deg, bcnt, N);
  k_bscan<<<1, 256, 0, stream>>>(bcnt, bbase, bfill, B);
  k_bin<<<(E + CH - 1) / CH, 512, 0, stream>>>(src, dst, bfill, bin, E);
  k_csr<<<B, 512, 0, stream>>>(bin, bbase, bcnt, dis, offsets, csr, N);
  k_mm1<<<(N + 127) / 128, 256, 0, stream>>>(x, W1, h1, N);
  k_pull1_mm2<<<2048, 256, 0, stream>>>(h1, csr, offsets, deg, dis, b1, W2, h2, N);
  k_pull2_lsm<<<2048, 256, 0, stream>>>(h2, csr, offsets, deg, dis, b2, out, N);
}

// Round 6
// 354.168 us; speedup vs baseline: 4.8035x; 1.3437x over previous
//
#include <hip/hip_runtime.h>
#include <hip/hip_bf16.h>

#define FIN 512
#define HD 32
#define BNODES 512   // nodes per dst-bucket (bucket = dst >> 9)
#define CH 8192      // edges per bin chunk

// ---------------- bucket counts straight from edges (196-bin LDS histogram) ----------------
__global__ __launch_bounds__(256) void k_bktcnt(const int* __restrict__ dst, int* __restrict__ bcnt, int E) {
  __shared__ int h[256];
  int t = threadIdx.x;
  h[t] = 0;
  __syncthreads();
  int i = blockIdx.x * 256 + t, stride = gridDim.x * 256;
  for (; i < E; i += stride) atomicAdd(&h[dst[i] >> 9], 1);
  __syncthreads();
  if (h[t]) atomicAdd(&bcnt[t], h[t]);
}

// exclusive scan over B (<=256) buckets; init fill cursors
__global__ __launch_bounds__(256) void k_bscan(const int* __restrict__ bcnt, int* bbase, int* bfill, int B) {
  __shared__ int s[256];
  int t = threadIdx.x;
  int v = (t < B) ? bcnt[t] : 0;
  s[t] = v;
  __syncthreads();
  for (int o = 1; o < 256; o <<= 1) {
    int a = (t >= o) ? s[t - o] : 0;
    __syncthreads();
    s[t] += a;
    __syncthreads();
  }
  if (t < B) { bbase[t] = s[t] - v; bfill[t] = s[t] - v; }
}

// ---------------- phase 1: coarse bin (src,dst) grouped by dst-bucket ----------------
__global__ __launch_bounds__(512) void k_bin(const int* __restrict__ src, const int* __restrict__ dst,
                                             int* __restrict__ bfill, int2* __restrict__ bin, int E) {
  __shared__ int2 raw[CH];     // 64 KB
  __shared__ int cnt[256];
  __shared__ int gbase[256];
  int t = threadIdx.x;
  for (int cb = blockIdx.x * CH; cb < E; cb += gridDim.x * CH) {
    int n = E - cb; if (n > CH) n = CH;
    if (t < 256) cnt[t] = 0;
    __syncthreads();
    for (int j = t; j < n; j += 512) {
      int s = src[cb + j], d = dst[cb + j];
      raw[j] = make_int2(s, d);
      atomicAdd(&cnt[d >> 9], 1);
    }
    __syncthreads();
    if (t < 256) {
      int c = cnt[t];
      gbase[t] = (c > 0) ? atomicAdd(&bfill[t], c) : 0;
      cnt[t] = 0;  // reuse as in-chunk cursor
    }
    __syncthreads();
    for (int j = t; j < n; j += 512) {
      int2 e = raw[j];
      int b = e.y >> 9;
      int r = atomicAdd(&cnt[b], 1);
      bin[gbase[b] + r] = e;
    }
    __syncthreads();
  }
}

// ---------------- phase 2: per-bucket exact CSR (src-only) + deg/dis/offsets ----------------
// LDS histogram of dst-within-bucket IS the indegree -> deg_count kernel deleted.
__global__ __launch_bounds__(512) void k_csr(const int2* __restrict__ bin, const int* __restrict__ bbase,
                                             const int* __restrict__ bcnt, int* __restrict__ cntm1,
                                             float* __restrict__ dis, int* __restrict__ offsets,
                                             int* __restrict__ csr, int N) {
  __shared__ int cnt[BNODES];
  __shared__ int sc[BNODES];
  const int t = threadIdx.x;
  const int bkt = blockIdx.x;
  const int n0 = bkt * BNODES;
  int nn = N - n0; if (nn > BNODES) nn = BNODES;
  const int eb = bbase[bkt], ec = bcnt[bkt];

  cnt[t] = 0;
  __syncthreads();
  for (int j = t; j < ec; j += 512)
    atomicAdd(&cnt[bin[eb + j].y - n0], 1);
  __syncthreads();
  int v = cnt[t];
  if (t < nn) {
    cntm1[n0 + t] = v;                       // deg-1
    dis[n0 + t] = rsqrtf((float)(v + 1));    // deg^{-1/2} (deg>=1 incl. self-loop)
  }
  sc[t] = v;
  __syncthreads();
  for (int o = 1; o < 512; o <<= 1) {
    int a = (t >= o) ? sc[t - o] : 0;
    __syncthreads();
    sc[t] += a;
    __syncthreads();
  }
  int myoff = sc[t] - v;  // exclusive within bucket
  if (t < nn) offsets[n0 + t] = eb + myoff;
  cnt[t] = myoff;         // reuse as scatter cursor
  __syncthreads();
  for (int j = t; j < ec; j += 512) {
    int2 e = bin[eb + j];
    int pos = atomicAdd(&cnt[e.y - n0], 1);
    csr[eb + pos] = e.x;   // src only: 4 B/edge
  }
}

// ---------------- mm1: h1s = (x @ W1) * dis[row]  (pre-scaled rows) ----------------
#define KC 32
#define XSP 33
__global__ __launch_bounds__(256, 4) void k_mm1(const float* __restrict__ x, const float* __restrict__ W1,
                                                const float* __restrict__ dis, float* __restrict__ h1s, int N) {
  __shared__ float xs[128 * XSP];
  __shared__ float wc[KC * HD];
  const int t = threadIdx.x;

  const int wv = t >> 6;
  const int lane = t & 63;
  const int rg = lane >> 3, cg = lane & 7;
  const int rbase = blockIdx.x * 128;
  const int arow = wv * 32 + rg * 4;

  const int ss = t & 7;
  const int sq = t >> 3;

  float acc[4][4];
#pragma unroll
  for (int i = 0; i < 4; ++i)
#pragma unroll
    for (int j = 0; j < 4; ++j) acc[i][j] = 0.f;

  for (int kc = 0; kc < FIN; kc += KC) {
    __syncthreads();
    ((float4*)wc)[t] = ((const float4*)(W1 + kc * HD))[t];
#pragma unroll
    for (int p = 0; p < 4; ++p) {
      int r = p * 32 + sq;
      int grow = rbase + r;
      float4 v = make_float4(0.f, 0.f, 0.f, 0.f);
      if (grow < N) v = *(const float4*)&x[(size_t)grow * FIN + kc + ss * 4];
      float* xr = &xs[r * XSP + ss * 4];
      xr[0] = v.x; xr[1] = v.y; xr[2] = v.z; xr[3] = v.w;
    }
    __syncthreads();

#pragma unroll 8
    for (int k = 0; k < KC; ++k) {
      float4 b = *(const float4*)&wc[k * HD + cg * 4];
      float a0 = xs[(arow + 0) * XSP + k];
      float a1 = xs[(arow + 1) * XSP + k];
      float a2 = xs[(arow + 2) * XSP + k];
      float a3 = xs[(arow + 3) * XSP + k];
      acc[0][0] += a0 * b.x; acc[0][1] += a0 * b.y; acc[0][2] += a0 * b.z; acc[0][3] += a0 * b.w;
      acc[1][0] += a1 * b.x; acc[1][1] += a1 * b.y; acc[1][2] += a1 * b.z; acc[1][3] += a1 * b.w;
      acc[2][0] += a2 * b.x; acc[2][1] += a2 * b.y; acc[2][2] += a2 * b.z; acc[2][3] += a2 * b.w;
      acc[3][0] += a3 * b.x; acc[3][1] += a3 * b.y; acc[3][2] += a3 * b.z; acc[3][3] += a3 * b.w;
    }
  }

#pragma unroll
  for (int i = 0; i < 4; ++i) {
    int row = rbase + arow + i;
    if (row < N) {
      float dr = dis[row];
      *(float4*)&h1s[(size_t)row * HD + cg * 4] =
          make_float4(acc[i][0] * dr, acc[i][1] * dr, acc[i][2] * dr, acc[i][3] * dr);
    }
  }
}

// ---------------- layer1: pure-add pull + bias + relu + mm2 -> h2s ----------------
// agg[i] = dis[i] * (sum_{src} h1s[src] + h1s[i]) ; h2s = (relu(agg+b1)@W2)*dis[i]
__global__ __launch_bounds__(256) void k_pull1_mm2(const float* __restrict__ h1s, const int* __restrict__ csr,
                                                   const int* __restrict__ offsets, const int* __restrict__ cntm1,
                                                   const float* __restrict__ dis, const float* __restrict__ b1,
                                                   const float* __restrict__ W2, float* __restrict__ h2s, int N) {
  __shared__ float w[HD * HD];
  __shared__ float bb[HD];
  int t = threadIdx.x;
  if (t < HD) bb[t] = b1[t];
  for (int i = t; i < HD * HD; i += 256) w[i] = W2[i];
  __syncthreads();

  int lane = t & 63, c = lane & 31;
  int halfId = (blockIdx.x * 4 + (t >> 6)) * 2 + (lane >> 5);
  int stride = gridDim.x * 8;
  for (int i = halfId; i < N; i += stride) {
    float s = h1s[(size_t)i * HD + c];  // self-loop
    int jb = offsets[i], cnt = cntm1[i];
    int j = 0;
    for (; j + 4 <= cnt; j += 4) {
      int s0 = csr[jb + j], s1 = csr[jb + j + 1], s2 = csr[jb + j + 2], s3 = csr[jb + j + 3];
      float g0 = h1s[(size_t)s0 * HD + c];
      float g1 = h1s[(size_t)s1 * HD + c];
      float g2 = h1s[(size_t)s2 * HD + c];
      float g3 = h1s[(size_t)s3 * HD + c];
      s += (g0 + g1) + (g2 + g3);
    }
    for (; j < cnt; ++j)
      s += h1s[(size_t)csr[jb + j] * HD + c];
    float d = dis[i];
    float tv = fmaxf(fmaf(d, s, bb[c]), 0.f);
    float a2 = 0.f;
#pragma unroll
    for (int k = 0; k < HD; ++k) a2 += __shfl(tv, k, 32) * w[k * HD + c];
    h2s[(size_t)i * HD + c] = a2 * d;
  }
}

// ---------------- layer2: pure-add pull + bias + log_softmax -> out ----------------
__global__ __launch_bounds__(256) void k_pull2_lsm(const float* __restrict__ h2s, const int* __restrict__ csr,
                                                   const int* __restrict__ offsets, const int* __restrict__ cntm1,
                                                   const float* __restrict__ dis, const float* __restrict__ b2,
                                                   float* __restrict__ out, int N) {
  __shared__ float bb[HD];
  int t = threadIdx.x;
  if (t < HD) bb[t] = b2[t];
  __syncthreads();

  int lane = t & 63, c = lane & 31;
  int halfId = (blockIdx.x * 4 + (t >> 6)) * 2 + (lane >> 5);
  int stride = gridDim.x * 8;
  for (int i = halfId; i < N; i += stride) {
    float s = h2s[(size_t)i * HD + c];  // self-loop
    int jb = offsets[i], cnt = cntm1[i];
    int j = 0;
    for (; j + 4 <= cnt; j += 4) {
      int s0 = csr[jb + j], s1 = csr[jb + j + 1], s2 = csr[jb + j + 2], s3 = csr[jb + j + 3];
      float g0 = h2s[(size_t)s0 * HD + c];
      float g1 = h2s[(size_t)s1 * HD + c];
      float g2 = h2s[(size_t)s2 * HD + c];
      float g3 = h2s[(size_t)s3 * HD + c];
      s += (g0 + g1) + (g2 + g3);
    }
    for (; j < cnt; ++j)
      s += h2s[(size_t)csr[jb + j] * HD + c];
    float v = fmaf(dis[i], s, bb[c]);
    float m = v;
    for (int off = 16; off; off >>= 1) m = fmaxf(m, __shfl_xor(m, off, 32));
    float ex = __expf(v - m);
    float sm = ex;
    for (int off = 16; off; off >>= 1) sm += __shfl_xor(sm, off, 32);
    out[(size_t)i * HD + c] = v - m - __logf(sm);
  }
}

extern "C" void kernel_launch(void* const* d_in, const int* in_sizes, int n_in,
                              void* d_out, int out_size, void* d_ws, size_t ws_size,
                              hipStream_t stream) {
  const float* x  = (const float*)d_in[0];
  const int*   ei = (const int*)d_in[1];
  const float* W1 = (const float*)d_in[2];
  const float* b1 = (const float*)d_in[3];
  const float* W2 = (const float*)d_in[4];
  const float* b2 = (const float*)d_in[5];
  float* out = (float*)d_out;

  const int H   = in_sizes[3];            // 32
  const int Fin = in_sizes[2] / H;        // 512
  const int N   = in_sizes[0] / Fin;      // 100000
  const int E   = in_sizes[1] / 2;        // 3200000
  const int* src = ei;
  const int* dst = ei + E;
  const int B   = (N + BNODES - 1) / BNODES;  // 196 buckets

  char* wsp = (char*)d_ws;
  size_t off = 0;
  auto nxt = [&](size_t bytes) { char* p = wsp + off; off = (off + bytes + 255) & ~(size_t)255; return p; };
  int*   bcnt    = (int*)  nxt(256 * 4);
  int*   bbase   = (int*)  nxt(256 * 4);
  int*   bfill   = (int*)  nxt(256 * 4);
  int*   cntm1   = (int*)  nxt((size_t)N * 4);
  float* dis     = (float*)nxt((size_t)N * 4);
  int*   offsets = (int*)  nxt((size_t)N * 4);
  int2*  bin     = (int2*) nxt((size_t)E * 8);
  int*   csr     = (int*)  nxt((size_t)E * 4);
  float* h1s     = (float*)nxt((size_t)N * HD * 4);
  float* h2s     = (float*)nxt((size_t)N * HD * 4);
  (void)ws_size; (void)n_in; (void)out_size;

  hipMemsetAsync(bcnt, 0, 256 * 4, stream);
  k_bktcnt<<<1024, 256, 0, stream>>>(dst, bcnt, E);
  k_bscan<<<1, 256, 0, stream>>>(bcnt, bbase, bfill, B);
  k_bin<<<(E + CH - 1) / CH, 512, 0, stream>>>(src, dst, bfill, bin, E);
  k_csr<<<B, 512, 0, stream>>>(bin, bbase, bcnt, cntm1, dis, offsets, csr, N);
  k_mm1<<<(N + 127) / 128, 256, 0, stream>>>(x, W1, dis, h1s, N);
  k_pull1_mm2<<<2048, 256, 0, stream>>>(h1s, csr, offsets, cntm1, dis, b1, W2, h2s, N);
  k_pull2_lsm<<<2048, 256, 0, stream>>>(h2s, csr, offsets, cntm1, dis, b2, out, N);
}

// Round 7
// 341.612 us; speedup vs baseline: 4.9800x; 1.0368x over previous
//
#include <hip/hip_runtime.h>
#include <hip/hip_bf16.h>

#define FIN 512
#define HD 32
#define BNODES 512   // nodes per dst-bucket (bucket = dst >> 9)
#define CH 8192      // edges per bin chunk
#define NHB 128      // partial-histogram blocks

__device__ inline unsigned short f2b(float f) {  // fp32 -> bf16 bits, RNE
  unsigned u = __float_as_uint(f);
  return (unsigned short)((u + 0x7FFFu + ((u >> 16) & 1u)) >> 16);
}
__device__ inline float b2f(unsigned short b) {
  return __uint_as_float((unsigned)b << 16);
}

// ---------------- per-block partial histograms over dst>>9 (no pre-zero needed) ----------------
__global__ __launch_bounds__(256) void k_bktcnt(const int* __restrict__ dst, int* __restrict__ hist, int E) {
  __shared__ int h[256];
  int t = threadIdx.x;
  h[t] = 0;
  __syncthreads();
  for (int i = blockIdx.x * 256 + t; i < E; i += gridDim.x * 256)
    atomicAdd(&h[dst[i] >> 9], 1);
  __syncthreads();
  hist[blockIdx.x * 256 + t] = h[t];
}

// sum partials -> bcnt; exclusive scan -> bbase; init bfill
__global__ __launch_bounds__(256) void k_bscan(const int* __restrict__ hist, int* __restrict__ bcnt,
                                               int* __restrict__ bbase, int* __restrict__ bfill) {
  __shared__ int s[256];
  int t = threadIdx.x;
  int v = 0;
  for (int b = 0; b < NHB; ++b) v += hist[b * 256 + t];
  bcnt[t] = v;
  s[t] = v;
  __syncthreads();
  for (int o = 1; o < 256; o <<= 1) {
    int a = (t >= o) ? s[t - o] : 0;
    __syncthreads();
    s[t] += a;
    __syncthreads();
  }
  bbase[t] = s[t] - v;
  bfill[t] = s[t] - v;
}

// ---------------- phase 1: coarse bin, packed 4B entries (src | dlow<<22) ----------------
__global__ __launch_bounds__(512) void k_bin(const int* __restrict__ src, const int* __restrict__ dst,
                                             int* __restrict__ bfill, int* __restrict__ bin, int E) {
  __shared__ int raw[CH];            // 32 KB packed entries
  __shared__ unsigned char bkt[CH];  // 8 KB bucket ids
  __shared__ int cnt[256];
  __shared__ int gbase[256];
  int t = threadIdx.x;
  for (int cb = blockIdx.x * CH; cb < E; cb += gridDim.x * CH) {
    int n = E - cb; if (n > CH) n = CH;
    if (t < 256) cnt[t] = 0;
    __syncthreads();
    for (int j = t; j < n; j += 512) {
      int s = src[cb + j], d = dst[cb + j];
      raw[j] = s | ((d & 511) << 22);
      bkt[j] = (unsigned char)(d >> 9);
      atomicAdd(&cnt[d >> 9], 1);
    }
    __syncthreads();
    if (t < 256) {
      int c = cnt[t];
      gbase[t] = (c > 0) ? atomicAdd(&bfill[t], c) : 0;
      cnt[t] = 0;  // reuse as in-chunk cursor
    }
    __syncthreads();
    for (int j = t; j < n; j += 512) {
      int b = bkt[j];
      int r = atomicAdd(&cnt[b], 1);
      bin[gbase[b] + r] = raw[j];
    }
    __syncthreads();
  }
}

// ---------------- phase 2: per-bucket exact CSR (src-only) + deg/dis/offsets ----------------
__global__ __launch_bounds__(512) void k_csr(const int* __restrict__ bin, const int* __restrict__ bbase,
                                             const int* __restrict__ bcnt, int* __restrict__ cntm1,
                                             float* __restrict__ dis, int* __restrict__ offsets,
                                             int* __restrict__ csr, int N) {
  __shared__ int cnt[BNODES];
  __shared__ int sc[BNODES];
  const int t = threadIdx.x;
  const int bkt = blockIdx.x;
  const int n0 = bkt * BNODES;
  int nn = N - n0; if (nn > BNODES) nn = BNODES;
  const int eb = bbase[bkt], ec = bcnt[bkt];

  cnt[t] = 0;
  __syncthreads();
  for (int j = t; j < ec; j += 512)
    atomicAdd(&cnt[(unsigned)bin[eb + j] >> 22], 1);
  __syncthreads();
  int v = cnt[t];
  if (t < nn) {
    cntm1[n0 + t] = v;                       // deg-1
    dis[n0 + t] = rsqrtf((float)(v + 1));    // deg^{-1/2}
  }
  sc[t] = v;
  __syncthreads();
  for (int o = 1; o < 512; o <<= 1) {
    int a = (t >= o) ? sc[t - o] : 0;
    __syncthreads();
    sc[t] += a;
    __syncthreads();
  }
  int myoff = sc[t] - v;
  if (t < nn) offsets[n0 + t] = eb + myoff;
  cnt[t] = myoff;  // reuse as scatter cursor
  __syncthreads();
  for (int j = t; j < ec; j += 512) {
    int e = bin[eb + j];
    int pos = atomicAdd(&cnt[(unsigned)e >> 22], 1);
    csr[eb + pos] = e & 0x3FFFFF;  // src only
  }
}

// ---------------- mm1: h1b = bf16((x @ W1) * dis[row]) ----------------
#define KC 32
#define XSP 33
__global__ __launch_bounds__(256, 4) void k_mm1(const float* __restrict__ x, const float* __restrict__ W1,
                                                const float* __restrict__ dis, unsigned short* __restrict__ h1b,
                                                int N) {
  __shared__ float xs[128 * XSP];
  __shared__ float wc[KC * HD];
  const int t = threadIdx.x;

  const int wv = t >> 6;
  const int lane = t & 63;
  const int rg = lane >> 3, cg = lane & 7;
  const int rbase = blockIdx.x * 128;
  const int arow = wv * 32 + rg * 4;

  const int ss = t & 7;
  const int sq = t >> 3;

  float acc[4][4];
#pragma unroll
  for (int i = 0; i < 4; ++i)
#pragma unroll
    for (int j = 0; j < 4; ++j) acc[i][j] = 0.f;

  for (int kc = 0; kc < FIN; kc += KC) {
    __syncthreads();
    ((float4*)wc)[t] = ((const float4*)(W1 + kc * HD))[t];
#pragma unroll
    for (int p = 0; p < 4; ++p) {
      int r = p * 32 + sq;
      int grow = rbase + r;
      float4 v = make_float4(0.f, 0.f, 0.f, 0.f);
      if (grow < N) v = *(const float4*)&x[(size_t)grow * FIN + kc + ss * 4];
      float* xr = &xs[r * XSP + ss * 4];
      xr[0] = v.x; xr[1] = v.y; xr[2] = v.z; xr[3] = v.w;
    }
    __syncthreads();

#pragma unroll 8
    for (int k = 0; k < KC; ++k) {
      float4 b = *(const float4*)&wc[k * HD + cg * 4];
      float a0 = xs[(arow + 0) * XSP + k];
      float a1 = xs[(arow + 1) * XSP + k];
      float a2 = xs[(arow + 2) * XSP + k];
      float a3 = xs[(arow + 3) * XSP + k];
      acc[0][0] += a0 * b.x; acc[0][1] += a0 * b.y; acc[0][2] += a0 * b.z; acc[0][3] += a0 * b.w;
      acc[1][0] += a1 * b.x; acc[1][1] += a1 * b.y; acc[1][2] += a1 * b.z; acc[1][3] += a1 * b.w;
      acc[2][0] += a2 * b.x; acc[2][1] += a2 * b.y; acc[2][2] += a2 * b.z; acc[2][3] += a2 * b.w;
      acc[3][0] += a3 * b.x; acc[3][1] += a3 * b.y; acc[3][2] += a3 * b.z; acc[3][3] += a3 * b.w;
    }
  }

#pragma unroll
  for (int i = 0; i < 4; ++i) {
    int row = rbase + arow + i;
    if (row < N) {
      float dr = dis[row];
      ushort4 pk;
      pk.x = f2b(acc[i][0] * dr);
      pk.y = f2b(acc[i][1] * dr);
      pk.z = f2b(acc[i][2] * dr);
      pk.w = f2b(acc[i][3] * dr);
      *(ushort4*)&h1b[(size_t)row * HD + cg * 4] = pk;
    }
  }
}

// ---------------- layer1: pure-add pull (bf16 gathers) + bias + relu + mm2 -> h2b ----------------
__global__ __launch_bounds__(256) void k_pull1_mm2(const unsigned short* __restrict__ h1b,
                                                   const int* __restrict__ csr, const int* __restrict__ offsets,
                                                   const int* __restrict__ cntm1, const float* __restrict__ dis,
                                                   const float* __restrict__ b1, const float* __restrict__ W2,
                                                   unsigned short* __restrict__ h2b, int N) {
  __shared__ float w[HD * HD];
  __shared__ float bb[HD];
  int t = threadIdx.x;
  if (t < HD) bb[t] = b1[t];
  for (int i = t; i < HD * HD; i += 256) w[i] = W2[i];
  __syncthreads();

  int lane = t & 63, c = lane & 31;
  int halfId = (blockIdx.x * 4 + (t >> 6)) * 2 + (lane >> 5);
  int stride = gridDim.x * 8;
  for (int i = halfId; i < N; i += stride) {
    float s = b2f(h1b[(size_t)i * HD + c]);  // self-loop
    int jb = offsets[i], cnt = cntm1[i];
    int j = 0;
    for (; j + 4 <= cnt; j += 4) {
      int s0 = csr[jb + j], s1 = csr[jb + j + 1], s2 = csr[jb + j + 2], s3 = csr[jb + j + 3];
      float g0 = b2f(h1b[(size_t)s0 * HD + c]);
      float g1 = b2f(h1b[(size_t)s1 * HD + c]);
      float g2 = b2f(h1b[(size_t)s2 * HD + c]);
      float g3 = b2f(h1b[(size_t)s3 * HD + c]);
      s += (g0 + g1) + (g2 + g3);
    }
    for (; j < cnt; ++j)
      s += b2f(h1b[(size_t)csr[jb + j] * HD + c]);
    float d = dis[i];
    float tv = fmaxf(fmaf(d, s, bb[c]), 0.f);
    float a2 = 0.f;
#pragma unroll
    for (int k = 0; k < HD; ++k) a2 += __shfl(tv, k, 32) * w[k * HD + c];
    h2b[(size_t)i * HD + c] = f2b(a2 * d);
  }
}

// ---------------- layer2: pure-add pull (bf16 gathers) + bias + log_softmax -> out ----------------
__global__ __launch_bounds__(256) void k_pull2_lsm(const unsigned short* __restrict__ h2b,
                                                   const int* __restrict__ csr, const int* __restrict__ offsets,
                                                   const int* __restrict__ cntm1, const float* __restrict__ dis,
                                                   const float* __restrict__ b2, float* __restrict__ out, int N) {
  __shared__ float bb[HD];
  int t = threadIdx.x;
  if (t < HD) bb[t] = b2[t];
  __syncthreads();

  int lane = t & 63, c = lane & 31;
  int halfId = (blockIdx.x * 4 + (t >> 6)) * 2 + (lane >> 5);
  int stride = gridDim.x * 8;
  for (int i = halfId; i < N; i += stride) {
    float s = b2f(h2b[(size_t)i * HD + c]);  // self-loop
    int jb = offsets[i], cnt = cntm1[i];
    int j = 0;
    for (; j + 4 <= cnt; j += 4) {
      int s0 = csr[jb + j], s1 = csr[jb + j + 1], s2 = csr[jb + j + 2], s3 = csr[jb + j + 3];
      float g0 = b2f(h2b[(size_t)s0 * HD + c]);
      float g1 = b2f(h2b[(size_t)s1 * HD + c]);
      float g2 = b2f(h2b[(size_t)s2 * HD + c]);
      float g3 = b2f(h2b[(size_t)s3 * HD + c]);
      s += (g0 + g1) + (g2 + g3);
    }
    for (; j < cnt; ++j)
      s += b2f(h2b[(size_t)csr[jb + j] * HD + c]);
    float v = fmaf(dis[i], s, bb[c]);
    float m = v;
    for (int off = 16; off; off >>= 1) m = fmaxf(m, __shfl_xor(m, off, 32));
    float ex = __expf(v - m);
    float sm = ex;
    for (int off = 16; off; off >>= 1) sm += __shfl_xor(sm, off, 32);
    out[(size_t)i * HD + c] = v - m - __logf(sm);
  }
}

extern "C" void kernel_launch(void* const* d_in, const int* in_sizes, int n_in,
                              void* d_out, int out_size, void* d_ws, size_t ws_size,
                              hipStream_t stream) {
  const float* x  = (const float*)d_in[0];
  const int*   ei = (const int*)d_in[1];
  const float* W1 = (const float*)d_in[2];
  const float* b1 = (const float*)d_in[3];
  const float* W2 = (const float*)d_in[4];
  const float* b2 = (const float*)d_in[5];
  float* out = (float*)d_out;

  const int H   = in_sizes[3];            // 32
  const int Fin = in_sizes[2] / H;        // 512
  const int N   = in_sizes[0] / Fin;      // 100000
  const int E   = in_sizes[1] / 2;        // 3200000
  const int* src = ei;
  const int* dst = ei + E;
  const int B   = (N + BNODES - 1) / BNODES;  // 196 buckets

  char* wsp = (char*)d_ws;
  size_t off = 0;
  auto nxt = [&](size_t bytes) { char* p = wsp + off; off = (off + bytes + 255) & ~(size_t)255; return p; };
  int*   hist    = (int*)  nxt((size_t)NHB * 256 * 4);
  int*   bcnt    = (int*)  nxt(256 * 4);
  int*   bbase   = (int*)  nxt(256 * 4);
  int*   bfill   = (int*)  nxt(256 * 4);
  int*   cntm1   = (int*)  nxt((size_t)N * 4);
  float* dis     = (float*)nxt((size_t)N * 4);
  int*   offsets = (int*)  nxt((size_t)N * 4);
  int*   bin     = (int*)  nxt((size_t)E * 4);
  int*   csr     = (int*)  nxt((size_t)E * 4);
  unsigned short* h1b = (unsigned short*)nxt((size_t)N * HD * 2);
  unsigned short* h2b = (unsigned short*)nxt((size_t)N * HD * 2);
  (void)ws_size; (void)n_in; (void)out_size;

  k_bktcnt<<<NHB, 256, 0, stream>>>(dst, hist, E);
  k_bscan<<<1, 256, 0, stream>>>(hist, bcnt, bbase, bfill);
  k_bin<<<(E + CH - 1) / CH, 512, 0, stream>>>(src, dst, bfill, bin, E);
  k_csr<<<B, 512, 0, stream>>>(bin, bbase, bcnt, cntm1, dis, offsets, csr, N);
  k_mm1<<<(N + 127) / 128, 256, 0, stream>>>(x, W1, dis, h1b, N);
  k_pull1_mm2<<<2048, 256, 0, stream>>>(h1b, csr, offsets, cntm1, dis, b1, W2, h2b, N);
  k_pull2_lsm<<<2048, 256, 0, stream>>>(h2b, csr, offsets, cntm1, dis, b2, out, N);
}

// Round 8
// 297.839 us; speedup vs baseline: 5.7119x; 1.1470x over previous
//
#include <hip/hip_runtime.h>
#include <hip/hip_bf16.h>

#define FIN 512
#define HD 32
#define BNODES 512   // nodes per dst-bucket (bucket = dst >> 9)
#define CH 8192      // edges per bin chunk
#define NHB 128      // partial-histogram blocks

typedef short s16x8 __attribute__((ext_vector_type(8)));
typedef float f32x4 __attribute__((ext_vector_type(4)));

__device__ inline unsigned short f2b(float f) {  // fp32 -> bf16 bits, RNE
  unsigned u = __float_as_uint(f);
  return (unsigned short)((u + 0x7FFFu + ((u >> 16) & 1u)) >> 16);
}
__device__ inline float b2f(unsigned short b) {
  return __uint_as_float((unsigned)b << 16);
}

// ---------------- per-block partial histograms over dst>>9 ----------------
__global__ __launch_bounds__(256) void k_bktcnt(const int* __restrict__ dst, int* __restrict__ hist, int E) {
  __shared__ int h[256];
  int t = threadIdx.x;
  h[t] = 0;
  __syncthreads();
  for (int i = blockIdx.x * 256 + t; i < E; i += gridDim.x * 256)
    atomicAdd(&h[dst[i] >> 9], 1);
  __syncthreads();
  hist[blockIdx.x * 256 + t] = h[t];
}

// sum partials -> bcnt; exclusive scan -> bbase; init bfill
__global__ __launch_bounds__(256) void k_bscan(const int* __restrict__ hist, int* __restrict__ bcnt,
                                               int* __restrict__ bbase, int* __restrict__ bfill) {
  __shared__ int s[256];
  int t = threadIdx.x;
  int v = 0;
  for (int b = 0; b < NHB; ++b) v += hist[b * 256 + t];
  bcnt[t] = v;
  s[t] = v;
  __syncthreads();
  for (int o = 1; o < 256; o <<= 1) {
    int a = (t >= o) ? s[t - o] : 0;
    __syncthreads();
    s[t] += a;
    __syncthreads();
  }
  bbase[t] = s[t] - v;
  bfill[t] = s[t] - v;
}

// ---------------- phase 1: coarse bin, packed 4B entries (src | dlow<<22) ----------------
__global__ __launch_bounds__(512) void k_bin(const int* __restrict__ src, const int* __restrict__ dst,
                                             int* __restrict__ bfill, int* __restrict__ bin, int E) {
  __shared__ int raw[CH];
  __shared__ unsigned char bkt[CH];
  __shared__ int cnt[256];
  __shared__ int gbase[256];
  int t = threadIdx.x;
  for (int cb = blockIdx.x * CH; cb < E; cb += gridDim.x * CH) {
    int n = E - cb; if (n > CH) n = CH;
    if (t < 256) cnt[t] = 0;
    __syncthreads();
    for (int j = t; j < n; j += 512) {
      int s = src[cb + j], d = dst[cb + j];
      raw[j] = s | ((d & 511) << 22);
      bkt[j] = (unsigned char)(d >> 9);
      atomicAdd(&cnt[d >> 9], 1);
    }
    __syncthreads();
    if (t < 256) {
      int c = cnt[t];
      gbase[t] = (c > 0) ? atomicAdd(&bfill[t], c) : 0;
      cnt[t] = 0;
    }
    __syncthreads();
    for (int j = t; j < n; j += 512) {
      int b = bkt[j];
      int r = atomicAdd(&cnt[b], 1);
      bin[gbase[b] + r] = raw[j];
    }
    __syncthreads();
  }
}

// ---------------- phase 2: per-bucket exact CSR (src-only) + deg/dis/offsets ----------------
__global__ __launch_bounds__(512) void k_csr(const int* __restrict__ bin, const int* __restrict__ bbase,
                                             const int* __restrict__ bcnt, int* __restrict__ cntm1,
                                             float* __restrict__ dis, int* __restrict__ offsets,
                                             int* __restrict__ csr, int N) {
  __shared__ int cnt[BNODES];
  __shared__ int sc[BNODES];
  const int t = threadIdx.x;
  const int bkt = blockIdx.x;
  const int n0 = bkt * BNODES;
  int nn = N - n0; if (nn > BNODES) nn = BNODES;
  const int eb = bbase[bkt], ec = bcnt[bkt];

  cnt[t] = 0;
  __syncthreads();
  for (int j = t; j < ec; j += 512)
    atomicAdd(&cnt[(unsigned)bin[eb + j] >> 22], 1);
  __syncthreads();
  int v = cnt[t];
  if (t < nn) {
    cntm1[n0 + t] = v;
    dis[n0 + t] = rsqrtf((float)(v + 1));
  }
  sc[t] = v;
  __syncthreads();
  for (int o = 1; o < 512; o <<= 1) {
    int a = (t >= o) ? sc[t - o] : 0;
    __syncthreads();
    sc[t] += a;
    __syncthreads();
  }
  int myoff = sc[t] - v;
  if (t < nn) offsets[n0 + t] = eb + myoff;
  cnt[t] = myoff;
  __syncthreads();
  for (int j = t; j < ec; j += 512) {
    int e = bin[eb + j];
    int pos = atomicAdd(&cnt[(unsigned)e >> 22], 1);
    csr[eb + pos] = e & 0x3FFFFF;
  }
}

// ---------------- mm1 via MFMA: h1b = bf16((x @ W1) * dis[row]) ----------------
// 512 thr = 8 waves; block tile 128 rows x 32 cols; wave = 16 rows.
// A-frag: xs[row][k] bf16, row=lane&15 (+wrow), k=(lane>>4)*8+i  (m97 pattern)
// B-frag: wT[col][k] bf16 (W^T), col=lane&15 (+16), same k mapping
// D: m=(lane>>4)*4+reg, n=lane&15  (m89 verified)
// Pads: XPAD=72 (144B rows), WPAD=520 (1040B rows) -> 2-way LDS conflicts (free).
#define XPAD 72
#define WPAD 520
__global__ __launch_bounds__(512) void k_mm1(const float* __restrict__ x, const float* __restrict__ W1,
                                             const float* __restrict__ dis, unsigned short* __restrict__ h1b,
                                             int N) {
  __shared__ unsigned short wT[32 * WPAD];   // 33.3 KB
  __shared__ unsigned short xs[128 * XPAD];  // 18.4 KB
  const int t = threadIdx.x;
  const int rbase = blockIdx.x * 128;

  // stage W^T once (bf16): read W1 row-major coalesced, scatter to wT
  for (int idx = t; idx < FIN * HD; idx += 512) {
    int k = idx >> 5, c = idx & 31;
    wT[c * WPAD + k] = f2b(W1[idx]);
  }

  const int lane = t & 63;
  const int wrow = (t >> 6) * 16;
  const int m16 = lane & 15;
  const int kg = lane >> 4;  // 0..3

  f32x4 acc0 = {0.f, 0.f, 0.f, 0.f};
  f32x4 acc1 = {0.f, 0.f, 0.f, 0.f};

  for (int kc = 0; kc < FIN; kc += 64) {
    __syncthreads();  // wT staged (first iter); xs frag-reads done (later iters)
    // stage x[128][kc..kc+64) -> bf16: 2048 float4 slots, 4 per thread
#pragma unroll
    for (int p = 0; p < 4; ++p) {
      int idx = p * 512 + t;
      int r = idx >> 4, kq = idx & 15;
      int grow = rbase + r;
      float4 v = (grow < N) ? *(const float4*)&x[(size_t)grow * FIN + kc + kq * 4]
                            : make_float4(0.f, 0.f, 0.f, 0.f);
      unsigned p0 = (unsigned)f2b(v.x) | ((unsigned)f2b(v.y) << 16);
      unsigned p1 = (unsigned)f2b(v.z) | ((unsigned)f2b(v.w) << 16);
      *(uint2*)&xs[r * XPAD + kq * 4] = make_uint2(p0, p1);
    }
    __syncthreads();

    s16x8 a0  = *(const s16x8*)&xs[(wrow + m16) * XPAD + kg * 8];
    s16x8 a1  = *(const s16x8*)&xs[(wrow + m16) * XPAD + 32 + kg * 8];
    s16x8 b00 = *(const s16x8*)&wT[m16 * WPAD + kc + kg * 8];
    s16x8 b01 = *(const s16x8*)&wT[(16 + m16) * WPAD + kc + kg * 8];
    s16x8 b10 = *(const s16x8*)&wT[m16 * WPAD + kc + 32 + kg * 8];
    s16x8 b11 = *(const s16x8*)&wT[(16 + m16) * WPAD + kc + 32 + kg * 8];
    acc0 = __builtin_amdgcn_mfma_f32_16x16x32_bf16(a0, b00, acc0, 0, 0, 0);
    acc1 = __builtin_amdgcn_mfma_f32_16x16x32_bf16(a0, b01, acc1, 0, 0, 0);
    acc0 = __builtin_amdgcn_mfma_f32_16x16x32_bf16(a1, b10, acc0, 0, 0, 0);
    acc1 = __builtin_amdgcn_mfma_f32_16x16x32_bf16(a1, b11, acc1, 0, 0, 0);
  }

#pragma unroll
  for (int r = 0; r < 4; ++r) {
    int row = rbase + wrow + kg * 4 + r;
    if (row < N) {
      float dr = dis[row];
      h1b[(size_t)row * HD + m16]      = f2b(acc0[r] * dr);
      h1b[(size_t)row * HD + 16 + m16] = f2b(acc1[r] * dr);
    }
  }
}

// ---------------- layer1: 2-row interleaved pull + bias + relu + mm2 -> h2b ----------------
__global__ __launch_bounds__(256) void k_pull1_mm2(const unsigned short* __restrict__ h1b,
                                                   const int* __restrict__ csr, const int* __restrict__ offsets,
                                                   const int* __restrict__ cntm1, const float* __restrict__ dis,
                                                   const float* __restrict__ b1, const float* __restrict__ W2,
                                                   unsigned short* __restrict__ h2b, int N) {
  __shared__ float w[HD * HD];
  __shared__ float bb[HD];
  int t = threadIdx.x;
  if (t < HD) bb[t] = b1[t];
  for (int i = t; i < HD * HD; i += 256) w[i] = W2[i];
  __syncthreads();

  int lane = t & 63, c = lane & 31;
  int halfId = (blockIdx.x * 4 + (t >> 6)) * 2 + (lane >> 5);
  int stride2 = gridDim.x * 16;
  for (int i0 = halfId * 2; i0 < N; i0 += stride2) {
    int i1 = i0 + 1;
    bool has1 = i1 < N;
    float s0 = b2f(h1b[(size_t)i0 * HD + c]);
    float s1 = has1 ? b2f(h1b[(size_t)i1 * HD + c]) : 0.f;
    int jb0 = offsets[i0], c0 = cntm1[i0];
    int jb1 = has1 ? offsets[i1] : 0, c1 = has1 ? cntm1[i1] : 0;
    int mn = min(c0, c1);
    int j = 0;
    for (; j + 4 <= mn; j += 4) {  // 8 independent gathers in flight
      int a0 = csr[jb0 + j], a1 = csr[jb0 + j + 1], a2 = csr[jb0 + j + 2], a3 = csr[jb0 + j + 3];
      int d0 = csr[jb1 + j], d1 = csr[jb1 + j + 1], d2 = csr[jb1 + j + 2], d3 = csr[jb1 + j + 3];
      float ga0 = b2f(h1b[(size_t)a0 * HD + c]);
      float ga1 = b2f(h1b[(size_t)a1 * HD + c]);
      float ga2 = b2f(h1b[(size_t)a2 * HD + c]);
      float ga3 = b2f(h1b[(size_t)a3 * HD + c]);
      float gd0 = b2f(h1b[(size_t)d0 * HD + c]);
      float gd1 = b2f(h1b[(size_t)d1 * HD + c]);
      float gd2 = b2f(h1b[(size_t)d2 * HD + c]);
      float gd3 = b2f(h1b[(size_t)d3 * HD + c]);
      s0 += (ga0 + ga1) + (ga2 + ga3);
      s1 += (gd0 + gd1) + (gd2 + gd3);
    }
    int j1 = j;
    for (; j + 4 <= c0; j += 4) {
      int a0 = csr[jb0 + j], a1 = csr[jb0 + j + 1], a2 = csr[jb0 + j + 2], a3 = csr[jb0 + j + 3];
      float ga0 = b2f(h1b[(size_t)a0 * HD + c]);
      float ga1 = b2f(h1b[(size_t)a1 * HD + c]);
      float ga2 = b2f(h1b[(size_t)a2 * HD + c]);
      float ga3 = b2f(h1b[(size_t)a3 * HD + c]);
      s0 += (ga0 + ga1) + (ga2 + ga3);
    }
    for (; j < c0; ++j) s0 += b2f(h1b[(size_t)csr[jb0 + j] * HD + c]);
    for (; j1 + 4 <= c1; j1 += 4) {
      int d0 = csr[jb1 + j1], d1 = csr[jb1 + j1 + 1], d2 = csr[jb1 + j1 + 2], d3 = csr[jb1 + j1 + 3];
      float gd0 = b2f(h1b[(size_t)d0 * HD + c]);
      float gd1 = b2f(h1b[(size_t)d1 * HD + c]);
      float gd2 = b2f(h1b[(size_t)d2 * HD + c]);
      float gd3 = b2f(h1b[(size_t)d3 * HD + c]);
      s1 += (gd0 + gd1) + (gd2 + gd3);
    }
    for (; j1 < c1; ++j1) s1 += b2f(h1b[(size_t)csr[jb1 + j1] * HD + c]);

    float dv0 = dis[i0];
    float dv1 = has1 ? dis[i1] : 0.f;
    float tv0 = fmaxf(fmaf(dv0, s0, bb[c]), 0.f);
    float tv1 = fmaxf(fmaf(dv1, s1, bb[c]), 0.f);
    float a20 = 0.f, a21 = 0.f;
#pragma unroll
    for (int k = 0; k < HD; ++k) {
      float wk = w[k * HD + c];
      a20 = fmaf(__shfl(tv0, k, 32), wk, a20);
      a21 = fmaf(__shfl(tv1, k, 32), wk, a21);
    }
    h2b[(size_t)i0 * HD + c] = f2b(a20 * dv0);
    if (has1) h2b[(size_t)i1 * HD + c] = f2b(a21 * dv1);
  }
}

// ---------------- layer2: 2-row interleaved pull + bias + log_softmax -> out ----------------
__global__ __launch_bounds__(256) void k_pull2_lsm(const unsigned short* __restrict__ h2b,
                                                   const int* __restrict__ csr, const int* __restrict__ offsets,
                                                   const int* __restrict__ cntm1, const float* __restrict__ dis,
                                                   const float* __restrict__ b2, float* __restrict__ out, int N) {
  __shared__ float bb[HD];
  int t = threadIdx.x;
  if (t < HD) bb[t] = b2[t];
  __syncthreads();

  int lane = t & 63, c = lane & 31;
  int halfId = (blockIdx.x * 4 + (t >> 6)) * 2 + (lane >> 5);
  int stride2 = gridDim.x * 16;
  for (int i0 = halfId * 2; i0 < N; i0 += stride2) {
    int i1 = i0 + 1;
    bool has1 = i1 < N;
    float s0 = b2f(h2b[(size_t)i0 * HD + c]);
    float s1 = has1 ? b2f(h2b[(size_t)i1 * HD + c]) : 0.f;
    int jb0 = offsets[i0], c0 = cntm1[i0];
    int jb1 = has1 ? offsets[i1] : 0, c1 = has1 ? cntm1[i1] : 0;
    int mn = min(c0, c1);
    int j = 0;
    for (; j + 4 <= mn; j += 4) {
      int a0 = csr[jb0 + j], a1 = csr[jb0 + j + 1], a2 = csr[jb0 + j + 2], a3 = csr[jb0 + j + 3];
      int d0 = csr[jb1 + j], d1 = csr[jb1 + j + 1], d2 = csr[jb1 + j + 2], d3 = csr[jb1 + j + 3];
      float ga0 = b2f(h2b[(size_t)a0 * HD + c]);
      float ga1 = b2f(h2b[(size_t)a1 * HD + c]);
      float ga2 = b2f(h2b[(size_t)a2 * HD + c]);
      float ga3 = b2f(h2b[(size_t)a3 * HD + c]);
      float gd0 = b2f(h2b[(size_t)d0 * HD + c]);
      float gd1 = b2f(h2b[(size_t)d1 * HD + c]);
      float gd2 = b2f(h2b[(size_t)d2 * HD + c]);
      float gd3 = b2f(h2b[(size_t)d3 * HD + c]);
      s0 += (ga0 + ga1) + (ga2 + ga3);
      s1 += (gd0 + gd1) + (gd2 + gd3);
    }
    int j1 = j;
    for (; j + 4 <= c0; j += 4) {
      int a0 = csr[jb0 + j], a1 = csr[jb0 + j + 1], a2 = csr[jb0 + j + 2], a3 = csr[jb0 + j + 3];
      float ga0 = b2f(h2b[(size_t)a0 * HD + c]);
      float ga1 = b2f(h2b[(size_t)a1 * HD + c]);
      float ga2 = b2f(h2b[(size_t)a2 * HD + c]);
      float ga3 = b2f(h2b[(size_t)a3 * HD + c]);
      s0 += (ga0 + ga1) + (ga2 + ga3);
    }
    for (; j < c0; ++j) s0 += b2f(h2b[(size_t)csr[jb0 + j] * HD + c]);
    for (; j1 + 4 <= c1; j1 += 4) {
      int d0 = csr[jb1 + j1], d1 = csr[jb1 + j1 + 1], d2 = csr[jb1 + j1 + 2], d3 = csr[jb1 + j1 + 3];
      float gd0 = b2f(h2b[(size_t)d0 * HD + c]);
      float gd1 = b2f(h2b[(size_t)d1 * HD + c]);
      float gd2 = b2f(h2b[(size_t)d2 * HD + c]);
      float gd3 = b2f(h2b[(size_t)d3 * HD + c]);
      s1 += (gd0 + gd1) + (gd2 + gd3);
    }
    for (; j1 < c1; ++j1) s1 += b2f(h2b[(size_t)csr[jb1 + j1] * HD + c]);

    float v0 = fmaf(dis[i0], s0, bb[c]);
    float v1 = has1 ? fmaf(dis[i1], s1, bb[c]) : 0.f;
    float m0 = v0, m1 = v1;
    for (int off = 16; off; off >>= 1) {
      m0 = fmaxf(m0, __shfl_xor(m0, off, 32));
      m1 = fmaxf(m1, __shfl_xor(m1, off, 32));
    }
    float e0 = __expf(v0 - m0), e1 = __expf(v1 - m1);
    float sm0 = e0, sm1 = e1;
    for (int off = 16; off; off >>= 1) {
      sm0 += __shfl_xor(sm0, off, 32);
      sm1 += __shfl_xor(sm1, off, 32);
    }
    out[(size_t)i0 * HD + c] = v0 - m0 - __logf(sm0);
    if (has1) out[(size_t)i1 * HD + c] = v1 - m1 - __logf(sm1);
  }
}

extern "C" void kernel_launch(void* const* d_in, const int* in_sizes, int n_in,
                              void* d_out, int out_size, void* d_ws, size_t ws_size,
                              hipStream_t stream) {
  const float* x  = (const float*)d_in[0];
  const int*   ei = (const int*)d_in[1];
  const float* W1 = (const float*)d_in[2];
  const float* b1 = (const float*)d_in[3];
  const float* W2 = (const float*)d_in[4];
  const float* b2 = (const float*)d_in[5];
  float* out = (float*)d_out;

  const int H   = in_sizes[3];            // 32
  const int Fin = in_sizes[2] / H;        // 512
  const int N   = in_sizes[0] / Fin;      // 100000
  const int E   = in_sizes[1] / 2;        // 3200000
  const int* src = ei;
  const int* dst = ei + E;
  const int B   = (N + BNODES - 1) / BNODES;  // 196 buckets

  char* wsp = (char*)d_ws;
  size_t off = 0;
  auto nxt = [&](size_t bytes) { char* p = wsp + off; off = (off + bytes + 255) & ~(size_t)255; return p; };
  int*   hist    = (int*)  nxt((size_t)NHB * 256 * 4);
  int*   bcnt    = (int*)  nxt(256 * 4);
  int*   bbase   = (int*)  nxt(256 * 4);
  int*   bfill   = (int*)  nxt(256 * 4);
  int*   cntm1   = (int*)  nxt((size_t)N * 4);
  float* dis     = (float*)nxt((size_t)N * 4);
  int*   offsets = (int*)  nxt((size_t)N * 4);
  int*   bin     = (int*)  nxt((size_t)E * 4);
  int*   csr     = (int*)  nxt((size_t)E * 4);
  unsigned short* h1b = (unsigned short*)nxt((size_t)N * HD * 2);
  unsigned short* h2b = (unsigned short*)nxt((size_t)N * HD * 2);
  (void)ws_size; (void)n_in; (void)out_size;

  k_bktcnt<<<NHB, 256, 0, stream>>>(dst, hist, E);
  k_bscan<<<1, 256, 0, stream>>>(hist, bcnt, bbase, bfill);
  k_bin<<<(E + CH - 1) / CH, 512, 0, stream>>>(src, dst, bfill, bin, E);
  k_csr<<<B, 512, 0, stream>>>(bin, bbase, bcnt, cntm1, dis, offsets, csr, N);
  k_mm1<<<(N + 127) / 128, 512, 0, stream>>>(x, W1, dis, h1b, N);
  k_pull1_mm2<<<2048, 256, 0, stream>>>(h1b, csr, offsets, cntm1, dis, b1, W2, h2b, N);
  k_pull2_lsm<<<2048, 256, 0, stream>>>(h2b, csr, offsets, cntm1, dis, b2, out, N);
}

// Round 9
// 259.404 us; speedup vs baseline: 6.5582x; 1.1482x over previous
//
#include <hip/hip_runtime.h>
#include <hip/hip_bf16.h>

#define FIN 512
#define HD 32
#define BNODES 512   // nodes per dst-bucket (bucket = dst >> 9)
#define CH 8192      // edges per bin chunk
#define NHB 128      // partial-histogram blocks

typedef short s16x8 __attribute__((ext_vector_type(8)));
typedef float f32x4 __attribute__((ext_vector_type(4)));

__device__ inline unsigned short f2b(float f) {  // fp32 -> bf16 bits, RNE
  unsigned u = __float_as_uint(f);
  return (unsigned short)((u + 0x7FFFu + ((u >> 16) & 1u)) >> 16);
}
__device__ inline float b2f(unsigned short b) {
  return __uint_as_float((unsigned)b << 16);
}
__device__ inline float b2f_lo(unsigned u) { return __uint_as_float(u << 16); }
__device__ inline float b2f_hi(unsigned u) { return __uint_as_float(u & 0xFFFF0000u); }

// ---------------- per-block partial histograms over dst>>9 ----------------
__global__ __launch_bounds__(256) void k_bktcnt(const int* __restrict__ dst, int* __restrict__ hist, int E) {
  __shared__ int h[256];
  int t = threadIdx.x;
  h[t] = 0;
  __syncthreads();
  for (int i = blockIdx.x * 256 + t; i < E; i += gridDim.x * 256)
    atomicAdd(&h[dst[i] >> 9], 1);
  __syncthreads();
  hist[blockIdx.x * 256 + t] = h[t];
}

// sum partials -> bcnt; exclusive scan -> bbase; init bfill
__global__ __launch_bounds__(256) void k_bscan(const int* __restrict__ hist, int* __restrict__ bcnt,
                                               int* __restrict__ bbase, int* __restrict__ bfill) {
  __shared__ int s[256];
  int t = threadIdx.x;
  int v = 0;
  for (int b = 0; b < NHB; ++b) v += hist[b * 256 + t];
  bcnt[t] = v;
  s[t] = v;
  __syncthreads();
  for (int o = 1; o < 256; o <<= 1) {
    int a = (t >= o) ? s[t - o] : 0;
    __syncthreads();
    s[t] += a;
    __syncthreads();
  }
  bbase[t] = s[t] - v;
  bfill[t] = s[t] - v;
}

// ---------------- phase 1: coarse bin, packed 4B entries (src | dlow<<22) ----------------
__global__ __launch_bounds__(512) void k_bin(const int* __restrict__ src, const int* __restrict__ dst,
                                             int* __restrict__ bfill, int* __restrict__ bin, int E) {
  __shared__ int raw[CH];
  __shared__ unsigned char bkt[CH];
  __shared__ int cnt[256];
  __shared__ int gbase[256];
  int t = threadIdx.x;
  for (int cb = blockIdx.x * CH; cb < E; cb += gridDim.x * CH) {
    int n = E - cb; if (n > CH) n = CH;
    if (t < 256) cnt[t] = 0;
    __syncthreads();
    for (int j = t; j < n; j += 512) {
      int s = src[cb + j], d = dst[cb + j];
      raw[j] = s | ((d & 511) << 22);
      bkt[j] = (unsigned char)(d >> 9);
      atomicAdd(&cnt[d >> 9], 1);
    }
    __syncthreads();
    if (t < 256) {
      int c = cnt[t];
      gbase[t] = (c > 0) ? atomicAdd(&bfill[t], c) : 0;
      cnt[t] = 0;
    }
    __syncthreads();
    for (int j = t; j < n; j += 512) {
      int b = bkt[j];
      int r = atomicAdd(&cnt[b], 1);
      bin[gbase[b] + r] = raw[j];
    }
    __syncthreads();
  }
}

// ---------------- phase 2: per-bucket exact CSR (src-only) + deg/dis/offsets ----------------
__global__ __launch_bounds__(512) void k_csr(const int* __restrict__ bin, const int* __restrict__ bbase,
                                             const int* __restrict__ bcnt, int* __restrict__ cntm1,
                                             float* __restrict__ dis, int* __restrict__ offsets,
                                             int* __restrict__ csr, int N) {
  __shared__ int cnt[BNODES];
  __shared__ int sc[BNODES];
  const int t = threadIdx.x;
  const int bkt = blockIdx.x;
  const int n0 = bkt * BNODES;
  int nn = N - n0; if (nn > BNODES) nn = BNODES;
  const int eb = bbase[bkt], ec = bcnt[bkt];

  cnt[t] = 0;
  __syncthreads();
  for (int j = t; j < ec; j += 512)
    atomicAdd(&cnt[(unsigned)bin[eb + j] >> 22], 1);
  __syncthreads();
  int v = cnt[t];
  if (t < nn) {
    cntm1[n0 + t] = v;
    dis[n0 + t] = rsqrtf((float)(v + 1));
  }
  sc[t] = v;
  __syncthreads();
  for (int o = 1; o < 512; o <<= 1) {
    int a = (t >= o) ? sc[t - o] : 0;
    __syncthreads();
    sc[t] += a;
    __syncthreads();
  }
  int myoff = sc[t] - v;
  if (t < nn) offsets[n0 + t] = eb + myoff;
  cnt[t] = myoff;
  __syncthreads();
  for (int j = t; j < ec; j += 512) {
    int e = bin[eb + j];
    int pos = atomicAdd(&cnt[(unsigned)e >> 22], 1);
    csr[eb + pos] = e & 0x3FFFFF;
  }
}

// ---------------- mm1 via MFMA: h1b = bf16((x @ W1) * dis[row]) (R8, unchanged) ----------------
#define XPAD 72
#define WPAD 520
__global__ __launch_bounds__(512) void k_mm1(const float* __restrict__ x, const float* __restrict__ W1,
                                             const float* __restrict__ dis, unsigned short* __restrict__ h1b,
                                             int N) {
  __shared__ unsigned short wT[32 * WPAD];
  __shared__ unsigned short xs[128 * XPAD];
  const int t = threadIdx.x;
  const int rbase = blockIdx.x * 128;

  for (int idx = t; idx < FIN * HD; idx += 512) {
    int k = idx >> 5, c = idx & 31;
    wT[c * WPAD + k] = f2b(W1[idx]);
  }

  const int lane = t & 63;
  const int wrow = (t >> 6) * 16;
  const int m16 = lane & 15;
  const int kg = lane >> 4;

  f32x4 acc0 = {0.f, 0.f, 0.f, 0.f};
  f32x4 acc1 = {0.f, 0.f, 0.f, 0.f};

  for (int kc = 0; kc < FIN; kc += 64) {
    __syncthreads();
#pragma unroll
    for (int p = 0; p < 4; ++p) {
      int idx = p * 512 + t;
      int r = idx >> 4, kq = idx & 15;
      int grow = rbase + r;
      float4 v = (grow < N) ? *(const float4*)&x[(size_t)grow * FIN + kc + kq * 4]
                            : make_float4(0.f, 0.f, 0.f, 0.f);
      unsigned p0 = (unsigned)f2b(v.x) | ((unsigned)f2b(v.y) << 16);
      unsigned p1 = (unsigned)f2b(v.z) | ((unsigned)f2b(v.w) << 16);
      *(uint2*)&xs[r * XPAD + kq * 4] = make_uint2(p0, p1);
    }
    __syncthreads();

    s16x8 a0  = *(const s16x8*)&xs[(wrow + m16) * XPAD + kg * 8];
    s16x8 a1  = *(const s16x8*)&xs[(wrow + m16) * XPAD + 32 + kg * 8];
    s16x8 b00 = *(const s16x8*)&wT[m16 * WPAD + kc + kg * 8];
    s16x8 b01 = *(const s16x8*)&wT[(16 + m16) * WPAD + kc + kg * 8];
    s16x8 b10 = *(const s16x8*)&wT[m16 * WPAD + kc + 32 + kg * 8];
    s16x8 b11 = *(const s16x8*)&wT[(16 + m16) * WPAD + kc + 32 + kg * 8];
    acc0 = __builtin_amdgcn_mfma_f32_16x16x32_bf16(a0, b00, acc0, 0, 0, 0);
    acc1 = __builtin_amdgcn_mfma_f32_16x16x32_bf16(a0, b01, acc1, 0, 0, 0);
    acc0 = __builtin_amdgcn_mfma_f32_16x16x32_bf16(a1, b10, acc0, 0, 0, 0);
    acc1 = __builtin_amdgcn_mfma_f32_16x16x32_bf16(a1, b11, acc1, 0, 0, 0);
  }

#pragma unroll
  for (int r = 0; r < 4; ++r) {
    int row = rbase + wrow + kg * 4 + r;
    if (row < N) {
      float dr = dis[row];
      h1b[(size_t)row * HD + m16]      = f2b(acc0[r] * dr);
      h1b[(size_t)row * HD + 16 + m16] = f2b(acc1[r] * dr);
    }
  }
}

// ---------------- wide-gather pull core: 8 edges x 16B per half-wave instr ----------------
// Lane L (0..31 in half-wave): edge slot es=L>>2, col-group cg=L&3 (16B of 64B row).
// acc[8] = cols cg*8..cg*8+7 partial sums over edge slots es, es+8, ...
// Then butterfly (xor 4,8,16) over slots + 8-shfl redistribution to lane=col.
__device__ inline float pull_row(const unsigned short* __restrict__ h, const int* __restrict__ csr,
                                 int jb, int cnt, int L, int es, int cg) {
  float a0 = 0.f, a1 = 0.f, a2 = 0.f, a3 = 0.f, a4 = 0.f, a5 = 0.f, a6 = 0.f, a7 = 0.f;
  for (int j = 0; j < cnt; j += 8) {
    int eidx = j + es;
    int sidx = csr[jb + min(eidx, cnt - 1)];
    uint4 u = *(const uint4*)&h[(size_t)sidx * HD + cg * 8];
    if (eidx >= cnt) u = make_uint4(0, 0, 0, 0);
    a0 += b2f_lo(u.x); a1 += b2f_hi(u.x);
    a2 += b2f_lo(u.y); a3 += b2f_hi(u.y);
    a4 += b2f_lo(u.z); a5 += b2f_hi(u.z);
    a6 += b2f_lo(u.w); a7 += b2f_hi(u.w);
  }
  // sum over the 8 edge slots (lanes xor 4,8,16 share cg)
#pragma unroll
  for (int o = 4; o <= 16; o <<= 1) {
    a0 += __shfl_xor(a0, o, 32); a1 += __shfl_xor(a1, o, 32);
    a2 += __shfl_xor(a2, o, 32); a3 += __shfl_xor(a3, o, 32);
    a4 += __shfl_xor(a4, o, 32); a5 += __shfl_xor(a5, o, 32);
    a6 += __shfl_xor(a6, o, 32); a7 += __shfl_xor(a7, o, 32);
  }
  // redistribute: col=L lives in element (L&7) of lane (L>>3) (cg = L>>3)
  int srcl = L >> 3;
  int sel = L & 7;
  float sum = __shfl(a0, srcl, 32);
  float c1 = __shfl(a1, srcl, 32); sum = (sel == 1) ? c1 : sum;
  float c2 = __shfl(a2, srcl, 32); sum = (sel == 2) ? c2 : sum;
  float c3 = __shfl(a3, srcl, 32); sum = (sel == 3) ? c3 : sum;
  float c4 = __shfl(a4, srcl, 32); sum = (sel == 4) ? c4 : sum;
  float c5 = __shfl(a5, srcl, 32); sum = (sel == 5) ? c5 : sum;
  float c6 = __shfl(a6, srcl, 32); sum = (sel == 6) ? c6 : sum;
  float c7 = __shfl(a7, srcl, 32); sum = (sel == 7) ? c7 : sum;
  return sum;
}

// ---------------- layer1: wide pull + bias + relu + mm2 -> h2b ----------------
__global__ __launch_bounds__(256) void k_pull1_mm2(const unsigned short* __restrict__ h1b,
                                                   const int* __restrict__ csr, const int* __restrict__ offsets,
                                                   const int* __restrict__ cntm1, const float* __restrict__ dis,
                                                   const float* __restrict__ b1, const float* __restrict__ W2,
                                                   unsigned short* __restrict__ h2b, int N) {
  __shared__ float w[HD * HD];
  __shared__ float bb[HD];
  int t = threadIdx.x;
  if (t < HD) bb[t] = b1[t];
  for (int i = t; i < HD * HD; i += 256) w[i] = W2[i];
  __syncthreads();

  int lane = t & 63, L = lane & 31;
  int es = L >> 2, cg = L & 3;
  int halfId = (blockIdx.x * 4 + (t >> 6)) * 2 + (lane >> 5);
  int stride = gridDim.x * 8;
  for (int i = halfId; i < N; i += stride) {
    float sum = pull_row(h1b, csr, offsets[i], cntm1[i], L, es, cg);
    float self = b2f(h1b[(size_t)i * HD + L]);
    float d = dis[i];
    float tv = fmaxf(fmaf(d, sum + self, bb[L]), 0.f);
    float a2 = 0.f;
#pragma unroll
    for (int k = 0; k < HD; ++k) a2 = fmaf(__shfl(tv, k, 32), w[k * HD + L], a2);
    h2b[(size_t)i * HD + L] = f2b(a2 * d);
  }
}

// ---------------- layer2: wide pull + bias + log_softmax -> out ----------------
__global__ __launch_bounds__(256) void k_pull2_lsm(const unsigned short* __restrict__ h2b,
                                                   const int* __restrict__ csr, const int* __restrict__ offsets,
                                                   const int* __restrict__ cntm1, const float* __restrict__ dis,
                                                   const float* __restrict__ b2, float* __restrict__ out, int N) {
  __shared__ float bb[HD];
  int t = threadIdx.x;
  if (t < HD) bb[t] = b2[t];
  __syncthreads();

  int lane = t & 63, L = lane & 31;
  int es = L >> 2, cg = L & 3;
  int halfId = (blockIdx.x * 4 + (t >> 6)) * 2 + (lane >> 5);
  int stride = gridDim.x * 8;
  for (int i = halfId; i < N; i += stride) {
    float sum = pull_row(h2b, csr, offsets[i], cntm1[i], L, es, cg);
    float self = b2f(h2b[(size_t)i * HD + L]);
    float v = fmaf(dis[i], sum + self, bb[L]);
    float m = v;
    for (int off = 16; off; off >>= 1) m = fmaxf(m, __shfl_xor(m, off, 32));
    float ex = __expf(v - m);
    float sm = ex;
    for (int off = 16; off; off >>= 1) sm += __shfl_xor(sm, off, 32);
    out[(size_t)i * HD + L] = v - m - __logf(sm);
  }
}

extern "C" void kernel_launch(void* const* d_in, const int* in_sizes, int n_in,
                              void* d_out, int out_size, void* d_ws, size_t ws_size,
                              hipStream_t stream) {
  const float* x  = (const float*)d_in[0];
  const int*   ei = (const int*)d_in[1];
  const float* W1 = (const float*)d_in[2];
  const float* b1 = (const float*)d_in[3];
  const float* W2 = (const float*)d_in[4];
  const float* b2 = (const float*)d_in[5];
  float* out = (float*)d_out;

  const int H   = in_sizes[3];            // 32
  const int Fin = in_sizes[2] / H;        // 512
  const int N   = in_sizes[0] / Fin;      // 100000
  const int E   = in_sizes[1] / 2;        // 3200000
  const int* src = ei;
  const int* dst = ei + E;
  const int B   = (N + BNODES - 1) / BNODES;  // 196 buckets

  char* wsp = (char*)d_ws;
  size_t off = 0;
  auto nxt = [&](size_t bytes) { char* p = wsp + off; off = (off + bytes + 255) & ~(size_t)255; return p; };
  int*   hist    = (int*)  nxt((size_t)NHB * 256 * 4);
  int*   bcnt    = (int*)  nxt(256 * 4);
  int*   bbase   = (int*)  nxt(256 * 4);
  int*   bfill   = (int*)  nxt(256 * 4);
  int*   cntm1   = (int*)  nxt((size_t)N * 4);
  float* dis     = (float*)nxt((size_t)N * 4);
  int*   offsets = (int*)  nxt((size_t)N * 4);
  int*   bin     = (int*)  nxt((size_t)E * 4);
  int*   csr     = (int*)  nxt((size_t)E * 4);
  unsigned short* h1b = (unsigned short*)nxt((size_t)N * HD * 2);
  unsigned short* h2b = (unsigned short*)nxt((size_t)N * HD * 2);
  (void)ws_size; (void)n_in; (void)out_size;

  k_bktcnt<<<NHB, 256, 0, stream>>>(dst, hist, E);
  k_bscan<<<1, 256, 0, stream>>>(hist, bcnt, bbase, bfill);
  k_bin<<<(E + CH - 1) / CH, 512, 0, stream>>>(src, dst, bfill, bin, E);
  k_csr<<<B, 512, 0, stream>>>(bin, bbase, bcnt, cntm1, dis, offsets, csr, N);
  k_mm1<<<(N + 127) / 128, 512, 0, stream>>>(x, W1, dis, h1b, N);
  k_pull1_mm2<<<2048, 256, 0, stream>>>(h1b, csr, offsets, cntm1, dis, b1, W2, h2b, N);
  k_pull2_lsm<<<2048, 256, 0, stream>>>(h2b, csr, offsets, cntm1, dis, b2, out, N);
}